// Round 7
// baseline (462.254 us; speedup 1.0000x reference)
//
#include <hip/hip_runtime.h>

// RNN: B=4096, T=512, I=15, H=64, O=1
// R6 = R5 per-wave structure, but 512-thread blocks carrying TWO independent
// 16-batch groups (waves 0-3 group A, waves 4-7 group B). 128 blocks -> 1
// block/CU -> 2 waves/SIMD from INDEPENDENT recurrences: stall interleaving
// with zero redundant FLOPs (R2/R4 bought TLP with redundancy and lost).
// Per wave: swapped MFMA preact^T[16j][16b] = Waug^T * [h|x]^T; h hi+lo in
// LDS (double-buffered per group); x direct global->reg pipeline; raw
// lgkmcnt-only s_barrier so x prefetch stays in flight.

#define T_STEPS 512
#define GPB 2             // batch groups per block
#define BPG 16            // batches per group
#define ROWSH 72          // shorts per h row (64 + 8 pad); 144B rows

typedef __attribute__((ext_vector_type(8))) short short8;
typedef __attribute__((ext_vector_type(4))) float float4v;

__device__ __forceinline__ short f2bf_rne(float f) {
    union { float f; unsigned u; } v; v.f = f;
    unsigned r = (v.u + 0x7FFFu + ((v.u >> 16) & 1u)) >> 16;
    return (short)r;
}
__device__ __forceinline__ float bf2f(short s) {
    union { float f; unsigned u; } v;
    v.u = ((unsigned)(unsigned short)s) << 16;
    return v.f;
}
// pack two f32 -> bf16 pair (round-half-up): 2 adds + 1 v_perm
__device__ __forceinline__ unsigned pk2(float f0, float f1) {
    union { float f; unsigned u; } a, b; a.f = f0; b.f = f1;
    return __builtin_amdgcn_perm(b.u + 0x8000u, a.u + 0x8000u, 0x07060302u);
}

__global__ __launch_bounds__(512, 2) void rnn_fused(
    const float* __restrict__ x,     // [4096][512][15]
    const float* __restrict__ W_ih,  // [64][15]
    const float* __restrict__ W_hh,  // [64][64]
    const float* __restrict__ b_ih,  // [64]
    const float* __restrict__ b_hh,  // [64]
    const float* __restrict__ fc_w,  // [1][64]
    const float* __restrict__ fc_b,  // [1]
    float* __restrict__ out)         // [4096]
{
    __shared__ __align__(16) short Ahi[GPB][2][BPG][ROWSH];
    __shared__ __align__(16) short Alo[GPB][2][BPG][ROWSH];

    const int tid  = threadIdx.x;
    const int wave = tid >> 6;        // 0..7
    const int grp  = wave >> 2;       // batch group 0/1
    const int wv   = wave & 3;        // j-split wave within group
    const int lane = tid & 63;
    const int q    = lane >> 4;
    const int n    = lane & 15;       // W col (j=16wv+n) on A-frag; batch on C/D
    const int jw   = wv * 16 + n;
    const int wj0  = wv * 16 + q * 4; // first j this lane OUTPUTS
    const int b0   = blockIdx.x * (GPB * BPG);
    const int bg   = b0 + grp * BPG;  // this group's batch base

    // zero LDS h state (h0 = 0; pad cols 64..71 stay 0)
    for (int idx = tid; idx < GPB * 2 * BPG * ROWSH; idx += 512) {
        ((short*)Ahi)[idx] = 0;
        ((short*)Alo)[idx] = 0;
    }

    // --- A-operand fragments: Waug[k][jw], k = 32c + 8q + e ---
    // chunk 2 (x-part) remapped to the register x-load order:
    //   q==0: e -> x[e];  q==1: e<4 -> x[8+e], e==4 -> 0, e>4 -> x[7+e]
    //   q>=2: zero (K-pad)
    short8 whi[3], wlo[2];
    for (int c = 0; c < 3; c++) {
        for (int e = 0; e < 8; e++) {
            float w = 0.f;
            if (c < 2) {
                int k = c * 32 + q * 8 + e;
                w = W_hh[jw * 64 + k];
            } else {
                int xk = -1;
                if (q == 0) xk = e;
                else if (q == 1) xk = (e < 4) ? (8 + e) : (e == 4 ? -1 : (7 + e));
                if (xk >= 0) w = W_ih[jw * 15 + xk];
            }
            short hi = f2bf_rne(w);
            whi[c][e] = hi;
            if (c < 2) wlo[c][e] = f2bf_rne(w - bf2f(hi));
        }
    }
    float bias_r[4];
    #pragma unroll
    for (int r = 0; r < 4; r++) bias_r[r] = b_ih[wj0 + r] + b_hh[wj0 + r];

    // x base pointers for this lane's B-fragment (batch row bg+n)
    const int offA = (q == 1) ? 8 : 0;
    const int offB = (q == 1) ? 11 : 4;
    const float* xpA = x + (size_t)(bg + n) * T_STEPS * 15 + offA;
    const float* xpB = x + (size_t)(bg + n) * T_STEPS * 15 + offB;

    // LDS read/write pointers (loop-invariant), within this group's buffers
    const short* rdh[2][2];
    const short* rdl[2][2];
    short* wrh[2];
    short* wrl[2];
    for (int pp = 0; pp < 2; pp++) {
        for (int c = 0; c < 2; c++) {
            rdh[pp][c] = &Ahi[grp][pp][n][32 * c + 8 * q];
            rdl[pp][c] = &Alo[grp][pp][n][32 * c + 8 * q];
        }
        wrh[pp] = &Ahi[grp][pp][n][wj0];
        wrl[pp] = &Alo[grp][pp][n][wj0];
    }

    // x register pipeline: xcur = x(0); (pa1,pb1) = x(1); (pa0,pb0) = x(2)
    float4v pa0, pb0, pa1, pb1;
    __builtin_memcpy(&pa1, xpA, 16);
    __builtin_memcpy(&pb1, xpB, 16);
    short8 xcur;
    {
        union { short8 s; unsigned u[4]; } xb;
        xb.u[0] = pk2(pa1.x, pa1.y); xb.u[1] = pk2(pa1.z, pa1.w);
        xb.u[2] = pk2(pb1.x, pb1.y); xb.u[3] = pk2(pb1.z, pb1.w);
        xcur = xb.s;
    }
    __builtin_memcpy(&pa1, xpA + 1 * 15, 16);
    __builtin_memcpy(&pb1, xpB + 1 * 15, 16);
    __builtin_memcpy(&pa0, xpA + 2 * 15, 16);
    __builtin_memcpy(&pb0, xpB + 2 * 15, 16);

    __syncthreads();   // zeros visible

    for (int t = 0; t < T_STEPS; t += 2) {
        #pragma unroll
        for (int u = 0; u < 2; u++) {
            const int p  = u, pn = u ^ 1;

            // issue h reads first; cover their latency with x work below
            short8 hhi0 = *(const short8*)rdh[p][0];
            short8 hhi1 = *(const short8*)rdh[p][1];
            short8 hlo0 = *(const short8*)rdl[p][0];
            short8 hlo1 = *(const short8*)rdl[p][1];

            // x-MFMA does not depend on LDS: give the scheduler LDS-free work
            float4v acc0 = {0.f, 0.f, 0.f, 0.f};
            float4v acc1 = {0.f, 0.f, 0.f, 0.f};
            float4v acc2 = {0.f, 0.f, 0.f, 0.f};
            acc0 = __builtin_amdgcn_mfma_f32_16x16x32_bf16(whi[2], xcur, acc0, 0, 0, 0);

            // rotate x pipeline (VALU on already-prefetched regs; LDS-free)
            {
                float4v& pa = u ? pa0 : pa1;
                float4v& pb = u ? pb0 : pb1;
                union { short8 s; unsigned uu[4]; } xb;
                xb.uu[0] = pk2(pa.x, pa.y); xb.uu[1] = pk2(pa.z, pa.w);
                xb.uu[2] = pk2(pb.x, pb.y); xb.uu[3] = pk2(pb.z, pb.w);
                int tl = t + u + 3; if (tl > T_STEPS - 1) tl = T_STEPS - 1;
                __builtin_memcpy(&pa, xpA + (size_t)tl * 15, 16);
                __builtin_memcpy(&pb, xpB + (size_t)tl * 15, 16);
                xcur = xb.s;
            }

            // h MFMAs: 3 independent chains
            acc0 = __builtin_amdgcn_mfma_f32_16x16x32_bf16(whi[0], hhi0, acc0, 0, 0, 0);
            acc1 = __builtin_amdgcn_mfma_f32_16x16x32_bf16(whi[0], hlo0, acc1, 0, 0, 0);
            acc2 = __builtin_amdgcn_mfma_f32_16x16x32_bf16(wlo[0], hhi0, acc2, 0, 0, 0);
            acc0 = __builtin_amdgcn_mfma_f32_16x16x32_bf16(whi[1], hhi1, acc0, 0, 0, 0);
            acc1 = __builtin_amdgcn_mfma_f32_16x16x32_bf16(whi[1], hlo1, acc1, 0, 0, 0);
            acc2 = __builtin_amdgcn_mfma_f32_16x16x32_bf16(wlo[1], hhi1, acc2, 0, 0, 0);

            // epilogue: D[row=4q+r -> j=wj0+r][col=n -> batch bg+n]
            unsigned hu[4], lu[4];
            #pragma unroll
            for (int r = 0; r < 4; r++) {
                float pre = (acc0[r] + acc1[r]) + (acc2[r] + bias_r[r]);
                float e = __builtin_exp2f(pre * 2.8853900817779268f);
                float h = 1.f - 2.f * __builtin_amdgcn_rcpf(e + 1.f);
                union { float f; unsigned u; } hv; hv.f = h;
                hu[r] = hv.u;
                union { float f; unsigned u; } hb; hb.u = hv.u & 0xFFFF0000u;
                union { float f; unsigned u; } rv; rv.f = h - hb.f;
                lu[r] = rv.u;
            }
            uint2 hiv, lov;
            hiv.x = (hu[0] >> 16) | (hu[1] & 0xFFFF0000u);
            hiv.y = (hu[2] >> 16) | (hu[3] & 0xFFFF0000u);
            lov.x = (lu[0] >> 16) | (lu[1] & 0xFFFF0000u);
            lov.y = (lu[2] >> 16) | (lu[3] & 0xFFFF0000u);
            *(uint2*)wrh[pn] = hiv;
            *(uint2*)wrl[pn] = lov;

            // raw barrier: drain LDS only; x global prefetch stays in flight
            asm volatile("s_waitcnt lgkmcnt(0)\n\ts_barrier" ::: "memory");
        }
    }

    // final head: h(511) lives in buf 0 (T even); last barrier made it visible
    if (tid < GPB * BPG) {
        const int g = tid >> 4, rr = tid & 15;
        float s = fc_b[0];
        for (int k = 0; k < 64; k++) {
            float hv = bf2f(Ahi[g][0][rr][k]) + bf2f(Alo[g][0][rr][k]);
            s += hv * fc_w[k];
        }
        out[b0 + tid] = s;
    }
}

extern "C" void kernel_launch(void* const* d_in, const int* in_sizes, int n_in,
                              void* d_out, int out_size, void* d_ws, size_t ws_size,
                              hipStream_t stream) {
    const float* x    = (const float*)d_in[0];
    const float* W_ih = (const float*)d_in[1];
    const float* W_hh = (const float*)d_in[2];
    const float* b_ih = (const float*)d_in[3];
    const float* b_hh = (const float*)d_in[4];
    const float* fc_w = (const float*)d_in[5];
    const float* fc_b = (const float*)d_in[6];
    float* out = (float*)d_out;

    rnn_fused<<<4096 / (GPB * BPG), 512, 0, stream>>>(x, W_ih, W_hh, b_ih, b_hh, fc_w, fc_b, out);
}